// Round 7
// baseline (1774.987 us; speedup 1.0000x reference)
//
#include <hip/hip_runtime.h>

// CompressiveMemory — round 12.
//  * gemm_qkv8 -> BK=32 with 64KB LDS dbuf => TWO blocks/CU (was 128KB, 1
//    block/CU, 2 waves/SIMD — every barrier/lgkm/vmcnt stall exposed; phase
//    cost ~2x the m201 reference). Cross-block overlap fills the drains.
//    Schedule = R6 schedule with unit=1 gload (8KB half-tile), vmcnt 6->3
//    (same 3-half-tiles-in-flight invariant, hazards re-verified). Same
//    global k-order => bit-identical (absmax canary 2.441406e-4).
//    Epilogue in 2 half-tile passes (transpose buffer is now 64KB).
//  * attn/bt8/seg_stats/prefix/prep unchanged.
//  * Ledger: R11 attn restructure was NEUTRAL — attn is not staging-bound;
//    attn & bt8 each sit just under the 134.5us top-5 cutoff.

#define H_ 16
#define SEG_ 512
#define NSEG_ 16
#define B_ 2
#define T_ 8192
#define D_ 1024
#define BT_ 16384

#define NPROJ ((size_t)BT_ * D_)   // 16,777,216
#define NW ((size_t)D_ * D_)       // 1,048,576

__device__ unsigned short g_qb[NPROJ], g_kb[NPROJ], g_vb[NPROJ];   // bf16 projections
__device__ unsigned short g_xh[NPROJ];
__device__ unsigned short g_wqkv[3 * NW];                          // [Wq;Wk;Wv] bf16
__device__ unsigned short g_ath[NPROJ], g_atl[NPROJ];
__device__ unsigned short g_woh[NW], g_wol[NW];
__device__ unsigned short g_vt[(size_t)512 * 64 * 512];            // per-tile V^T bf16
__device__ float g_M[(size_t)512 * 4096];
__device__ float g_z[(size_t)512 * 64];

typedef __attribute__((ext_vector_type(8))) short short8;
typedef __attribute__((ext_vector_type(8))) unsigned short ushort8;
typedef __attribute__((ext_vector_type(4))) float f32x4;

__device__ __forceinline__ float elu1(float x) {
    return x > 0.f ? x + 1.f : __expf(x);
}
__device__ __forceinline__ unsigned short f2bf(float x) {
    unsigned u = __float_as_uint(x);
    u += 0x7fffu + ((u >> 16) & 1u);           // RNE
    return (unsigned short)(u >> 16);
}
__device__ __forceinline__ float bf2f(unsigned short h) {
    return __uint_as_float((unsigned)h << 16);
}
__device__ __forceinline__ void load_lds16(const unsigned short* g, unsigned short* l) {
    __builtin_amdgcn_global_load_lds(
        (const __attribute__((address_space(1))) unsigned int*)g,
        (__attribute__((address_space(3))) unsigned int*)l, 16, 0, 0);
}
// ushort offset of (row, 8-ushort block blk) in a [*][64]-bf16 LDS tile,
// XOR-swizzled so column-slice b128 reads hit the uniform bank floor.
__device__ __forceinline__ int sz8(int row, int blk) {
    return row * 64 + ((blk ^ (row & 7)) << 3);
}

// Fused prologue: cast x, Wq, Wk, Wv to bf16; split Wout into hi/lo.
__global__ __launch_bounds__(256) void prep_cast(
    const float* __restrict__ x, const float* __restrict__ Wq,
    const float* __restrict__ Wk, const float* __restrict__ Wv,
    const float* __restrict__ Wout,
    unsigned short* __restrict__ xh, unsigned short* __restrict__ wqkv,
    unsigned short* __restrict__ woh, unsigned short* __restrict__ wol)
{
    const int b = blockIdx.x;
    const int nXB = (int)(NPROJ / 1024);           // 16384
    const int nWB = (int)(NW / 1024);              // 1024
    if (b < nXB + 3 * nWB) {
        const float* in;
        unsigned short* out;
        int i;
        if (b < nXB) {
            in = x; out = xh; i = (b * 256 + threadIdx.x) * 4;
        } else {
            const int wsel = (b - nXB) / nWB;      // 0,1,2
            const int wb   = (b - nXB) % nWB;
            in  = wsel == 0 ? Wq : (wsel == 1 ? Wk : Wv);
            out = wqkv + (size_t)wsel * NW;
            i = (wb * 256 + threadIdx.x) * 4;
        }
        float4 v = *(const float4*)(in + i);
        ushort4 h;
        h.x = f2bf(v.x); h.y = f2bf(v.y); h.z = f2bf(v.z); h.w = f2bf(v.w);
        *(ushort4*)(out + i) = h;
    } else {
        const int wb = b - nXB - 3 * nWB;
        const int i = (wb * 256 + threadIdx.x) * 4;
        float4 v = *(const float4*)(Wout + i);
        ushort4 h, l;
        h.x = f2bf(v.x); l.x = f2bf(v.x - bf2f(h.x));
        h.y = f2bf(v.y); l.y = f2bf(v.y - bf2f(h.y));
        h.z = f2bf(v.z); l.z = f2bf(v.z - bf2f(h.z));
        h.w = f2bf(v.w); l.w = f2bf(v.w - bf2f(h.w));
        *(ushort4*)(woh + i) = h;
        *(ushort4*)(wol + i) = l;
    }
}

// ---------------------------------------------------------------------------
// Fused QKV GEMM, 8-phase 256x256 pipeline, BK=32, 64KB dbuf (2 blocks/CU).
// C[m,n] = sum_k x[m,k]*Wqkv[n,k]; M=16384, N=3072, K=1024; bf16 out.
// LDS buffer: A 256x32 (16KB) + B 256x32 (16KB); dbuf = 64KB.
// Stage unit = 128 rows (8KB) = 1 global_load_lds per wave.
// ---------------------------------------------------------------------------

#define VMC(N) asm volatile("s_waitcnt vmcnt(" #N ")" ::: "memory")

#define QSTG_A(p, u, tt) \
    load_lds16(Aw + (size_t)(u) * 128 * 1024 + (tt) * 32, \
               &lds[(p) * 16384 + (u) * 4096 + w * 512])
#define QSTG_B(p, u, tt) \
    load_lds16(Bww + (size_t)(u) * 128 * 1024 + (tt) * 32, \
               &lds[(p) * 16384 + 8192 + (u) * 4096 + w * 512])

#define LDA(PBUF, MLO) do { \
    _Pragma("unroll") for (int m2 = 0; m2 < 4; ++m2) \
        a[m2] = *(const short8*)&lds[(PBUF) * 16384 + aoff + ((MLO) + m2) * 512]; \
} while (0)

#define LDB(PBUF) do { \
    _Pragma("unroll") for (int n2 = 0; n2 < 4; ++n2) \
        b[n2] = *(const short8*)&lds[(PBUF) * 16384 + boff + n2 * 512]; \
} while (0)

#define MFMA_QUAD(MLO, NLO) do { \
    _Pragma("unroll") for (int m2 = 0; m2 < 4; ++m2) \
    _Pragma("unroll") for (int n2 = 0; n2 < 2; ++n2) \
        acc[(MLO) + m2][(NLO) + n2] = __builtin_amdgcn_mfma_f32_16x16x32_bf16( \
            a[m2], b[(NLO) + n2], acc[(MLO) + m2][(NLO) + n2], 0, 0, 0); \
} while (0)

#define PH(MLO, NLO) do { \
    __builtin_amdgcn_s_barrier(); \
    asm volatile("s_waitcnt lgkmcnt(0)" ::: "memory"); \
    __builtin_amdgcn_sched_barrier(0); \
    __builtin_amdgcn_s_setprio(1); \
    MFMA_QUAD(MLO, NLO); \
    __builtin_amdgcn_s_setprio(0); \
    __builtin_amdgcn_sched_barrier(0); \
    __builtin_amdgcn_s_barrier(); \
} while (0)

__global__ __launch_bounds__(512, 4) void gemm_qkv8(
    const unsigned short* __restrict__ A, const unsigned short* __restrict__ Bw,
    unsigned short* __restrict__ Q, unsigned short* __restrict__ Kp,
    unsigned short* __restrict__ V)
{
    __shared__ unsigned short lds[32768];   // 64KB: [buf0 A|B][buf1 A|B]
    const int t = threadIdx.x, lane = t & 63, w = t >> 6;
    const int wave_m = w >> 2, wave_n = w & 3;

    // XCD-bijective swizzle: 768 blocks = 96 * 8.
    const int bid = blockIdx.x;
    const int sb = (bid & 7) * 96 + (bid >> 3);
    const int mb = sb / 12, nb = sb % 12;
    const int m0 = mb * 256, n0 = nb * 256;

    // staging per-lane constants (LDS linear; swizzle folded into global col)
    const int lrow = lane >> 2;                               // 0..15
    const int scol = ((lane & 3) ^ ((lrow >> 1) & 3)) * 8;    // blk ^ ((row>>1)&3)
    const unsigned short* Aw  = A  + (size_t)(m0 + w * 16 + lrow) * 1024 + scol;
    const unsigned short* Bww = Bw + (size_t)(n0 + w * 16 + lrow) * 1024 + scol;

    // frag-read per-lane ushort offsets (same involution)
    const int fr = lane & 15, g4 = lane >> 4;
    const int xo = (g4 ^ ((fr >> 1) & 3)) * 8;
    const int aoff = (wave_m * 128 + fr) * 32 + xo;
    const int boff = 8192 + (wave_n * 64 + fr) * 32 + xo;

    f32x4 acc[8][4];
#pragma unroll
    for (int i = 0; i < 8; ++i)
#pragma unroll
        for (int j = 0; j < 4; ++j) acc[i][j] = (f32x4)0.f;
    short8 a[4], b[4];

    // Prologue: tile0 (buf0) all 4 units + tile1 (buf1) B0,B1,A0 = 7 gloads.
    // VMC(3) -> tile0's 4 landed.
    QSTG_B(0, 0, 0); QSTG_B(0, 1, 0); QSTG_A(0, 0, 0); QSTG_A(0, 1, 0);
    QSTG_B(1, 0, 1); QSTG_B(1, 1, 1); QSTG_A(1, 0, 1);
    VMC(3);
    __builtin_amdgcn_s_barrier();

    // Main loop: 15 iterations (tiles 0..29 computed, 2..31 prefetched).
#pragma unroll 1
    for (int it = 0; it < 15; ++it) {
        const int t1 = 2 * it + 1, t2 = 2 * it + 2, t3 = 2 * it + 3;
        LDB(0); LDA(0, 0);
        QSTG_A(1, 1, t1);
        PH(0, 0);
        QSTG_B(0, 0, t2);
        PH(0, 2);
        LDA(0, 4);
        QSTG_B(0, 1, t2);
        PH(4, 0);
        QSTG_A(0, 0, t2);
        VMC(3);
        PH(4, 2);
        LDB(1); LDA(1, 0);
        QSTG_A(0, 1, t2);
        PH(0, 0);
        QSTG_B(1, 0, t3);
        PH(0, 2);
        LDA(1, 4);
        QSTG_B(1, 1, t3);
        PH(4, 0);
        QSTG_A(1, 0, t3);
        VMC(3);
        PH(4, 2);
    }
    // Final: tiles 30 (buf0) and 31 (buf1); only p1's stage remains.
    LDB(0); LDA(0, 0);
    QSTG_A(1, 1, 31);
    PH(0, 0);
    PH(0, 2);
    LDA(0, 4);
    PH(4, 0);
    VMC(0);
    PH(4, 2);
    LDB(1); LDA(1, 0);
    PH(0, 0);
    PH(0, 2);
    LDA(1, 4);
    PH(4, 0);
    PH(4, 2);

    // Epilogue: two half-tile passes (64KB buffer = 128 rows x 256 cols).
    // row&31 XOR on both sides (round 9 conflict fix).
    const int ccol = lane & 15, crow = (lane >> 4) * 4;
    const int which = n0 >> 10, col0 = n0 & 1023;
    unsigned short* outp = which == 0 ? Q : (which == 1 ? Kp : V);
    const int orow = t >> 2, och = (t & 3) * 64;   // 4 threads/row, 64 cols each
#pragma unroll 1
    for (int half = 0; half < 2; ++half) {
        __syncthreads();   // previous pass reads (or main loop) done
        if (wave_m == half) {
#pragma unroll
            for (int m = 0; m < 8; ++m)
#pragma unroll
                for (int n = 0; n < 4; ++n) {
                    const int col = wave_n * 64 + n * 16 + ccol;
                    const int cb = col >> 3, cl = col & 7;
#pragma unroll
                    for (int r = 0; r < 4; ++r) {
                        const int row = m * 16 + crow + r;   // 0..127 within half
                        lds[row * 256 + ((cb ^ (row & 31)) << 3) + cl] = f2bf(acc[m][n][r]);
                    }
                }
        }
        __syncthreads();
        unsigned short* gp = outp + (size_t)(m0 + half * 128 + orow) * 1024 + col0 + och;
#pragma unroll
        for (int u = 0; u < 64; u += 8) {
            const int bo = (och + u) >> 3;
            *(ushort8*)(gp + u) = *(const ushort8*)&lds[orow * 256 + ((bo ^ (orow & 31)) << 3)];
        }
    }
}

// ---------------------------------------------------------------------------
// Out-GEMM, 8-phase 256x256/BK=32 split-bf16 pipeline (unchanged, round 7).
// ---------------------------------------------------------------------------

#define OSTG(p, arrp, aroff, tt, u) \
    load_lds16(arrp + (size_t)(u) * 16 * 1024 + (tt) * 32, \
               &olds[(p) * 32768 + (aroff) + (w * 32 + (u) * 16) * 32])
#define OUNIT(p, arrp, aroff, tt) do { OSTG(p, arrp, aroff, tt, 0); OSTG(p, arrp, aroff, tt, 1); } while (0)

#define OLDA(PBUF, MLO) do { \
    _Pragma("unroll") for (int m2 = 0; m2 < 4; ++m2) { \
        ah[m2] = *(const short8*)&olds[(PBUF) * 32768 +         ao + ((MLO) + m2) * 512]; \
        al[m2] = *(const short8*)&olds[(PBUF) * 32768 +  8192 + ao + ((MLO) + m2) * 512]; \
    } \
} while (0)

#define OLDB(PBUF) do { \
    _Pragma("unroll") for (int n2 = 0; n2 < 4; ++n2) { \
        bh[n2] = *(const short8*)&olds[(PBUF) * 32768 + 16384 + bo + n2 * 512]; \
        bl[n2] = *(const short8*)&olds[(PBUF) * 32768 + 24576 + bo + n2 * 512]; \
    } \
} while (0)

#define OQUAD(MLO, NLO) do { \
    _Pragma("unroll") for (int m2 = 0; m2 < 4; ++m2) \
    _Pragma("unroll") for (int n2 = 0; n2 < 2; ++n2) { \
        acc[(MLO) + m2][(NLO) + n2] = __builtin_amdgcn_mfma_f32_16x16x32_bf16( \
            ah[m2], bh[(NLO) + n2], acc[(MLO) + m2][(NLO) + n2], 0, 0, 0); \
        acc[(MLO) + m2][(NLO) + n2] = __builtin_amdgcn_mfma_f32_16x16x32_bf16( \
            al[m2], bh[(NLO) + n2], acc[(MLO) + m2][(NLO) + n2], 0, 0, 0); \
        acc[(MLO) + m2][(NLO) + n2] = __builtin_amdgcn_mfma_f32_16x16x32_bf16( \
            ah[m2], bl[(NLO) + n2], acc[(MLO) + m2][(NLO) + n2], 0, 0, 0); \
    } \
} while (0)

#define OPH(MLO, NLO) do { \
    __builtin_amdgcn_s_barrier(); \
    asm volatile("s_waitcnt lgkmcnt(0)" ::: "memory"); \
    __builtin_amdgcn_sched_barrier(0); \
    __builtin_amdgcn_s_setprio(1); \
    OQUAD(MLO, NLO); \
    __builtin_amdgcn_s_setprio(0); \
    __builtin_amdgcn_sched_barrier(0); \
    __builtin_amdgcn_s_barrier(); \
} while (0)

__global__ __launch_bounds__(512, 2) void gemm_bt8(
    const unsigned short* __restrict__ Ah, const unsigned short* __restrict__ Al,
    const unsigned short* __restrict__ Bh, const unsigned short* __restrict__ Bl,
    float* __restrict__ C)
{
    __shared__ unsigned short olds[65536];   // 128KB: [buf0 Ah|Al|Bh|Bl][buf1 ...]
    const int t = threadIdx.x, lane = t & 63, w = t >> 6;
    const int wave_m = w >> 2, wave_n = w & 3;

    const int bid = blockIdx.x;
    const int sb = (bid & 7) * 32 + (bid >> 3);
    const int m0 = (sb >> 2) * 256, n0 = (sb & 3) * 256;

    const int lrow = lane >> 2;                               // 0..15
    const int lcol = ((lane & 3) ^ ((lane >> 3) & 3)) * 8;    // blk ^ ((row>>1)&3)
    const unsigned short* Ahp = Ah + (size_t)(m0 + w * 32 + lrow) * 1024 + lcol;
    const unsigned short* Alp = Al + (size_t)(m0 + w * 32 + lrow) * 1024 + lcol;
    const unsigned short* Bhp = Bh + (size_t)(n0 + w * 32 + lrow) * 1024 + lcol;
    const unsigned short* Blp = Bl + (size_t)(n0 + w * 32 + lrow) * 1024 + lcol;

    const int fr = lane & 15, g4 = lane >> 4;
    const int xo = (g4 ^ ((fr >> 1) & 3)) * 8;
    const int ao = (wave_m * 128 + fr) * 32 + xo;
    const int bo = (wave_n * 64 + fr) * 32 + xo;

    f32x4 acc[8][4];
#pragma unroll
    for (int i = 0; i < 8; ++i)
#pragma unroll
        for (int j = 0; j < 4; ++j) acc[i][j] = (f32x4)0.f;
    short8 ah[4], al[4], bh[4], bl[4];

    OUNIT(0, Bhp, 16384, 0); OUNIT(0, Blp, 24576, 0); OUNIT(0, Ahp, 0, 0); OUNIT(0, Alp, 8192, 0);
    OUNIT(1, Bhp, 16384, 1); OUNIT(1, Blp, 24576, 1); OUNIT(1, Ahp, 0, 1);
    VMC(6);
    __builtin_amdgcn_s_barrier();

#pragma unroll 1
    for (int it = 0; it < 15; ++it) {
        const int t1 = 2 * it + 1, t2 = 2 * it + 2, t3 = 2 * it + 3;
        OLDB(0); OLDA(0, 0);
        OUNIT(1, Alp, 8192, t1);
        OPH(0, 0);
        OUNIT(0, Bhp, 16384, t2);
        OPH(0, 2);
        OLDA(0, 4);
        OUNIT(0, Blp, 24576, t2);
        OPH(4, 0);
        OUNIT(0, Ahp, 0, t2);
        VMC(6);
        OPH(4, 2);
        OLDB(1); OLDA(1, 0);
        OUNIT(0, Alp, 8192, t2);
        OPH(0, 0);
        OUNIT(1, Bhp, 16384, t3);
        OPH(0, 2);
        OLDA(1, 4);
        OUNIT(1, Blp, 24576, t3);
        OPH(4, 0);
        OUNIT(1, Ahp, 0, t3);
        VMC(6);
        OPH(4, 2);
    }
    OLDB(0); OLDA(0, 0);
    OUNIT(1, Alp, 8192, 31);
    OPH(0, 0);
    OPH(0, 2);
    OLDA(0, 4);
    OPH(4, 0);
    VMC(0);
    OPH(4, 2);
    OLDB(1); OLDA(1, 0);
    OPH(0, 0);
    OPH(0, 2);
    OLDA(1, 4);
    OPH(4, 0);
    OPH(4, 2);

    const int ccol = lane & 15, crow = (lane >> 4) * 4;
#pragma unroll
    for (int m = 0; m < 8; ++m)
#pragma unroll
        for (int n = 0; n < 4; ++n) {
            float* cp = C + (size_t)(m0 + wave_m * 128 + m * 16 + crow) * 1024
                          + (n0 + wave_n * 64 + n * 16 + ccol);
#pragma unroll
            for (int r = 0; r < 4; ++r) cp[(size_t)r * 1024] = acc[m][n][r];
        }
}

// Per (b,h,seg): M_seg[d][v] = sk^T v, zsum[d], V^T bf16 tile — via MFMA.
__global__ __launch_bounds__(256) void seg_stats(
    const unsigned short* __restrict__ kproj, const unsigned short* __restrict__ vproj,
    float* __restrict__ Mseg, float* __restrict__ zsum,
    unsigned short* __restrict__ vtg)
{
    __shared__ unsigned short sm_kh[64 * 64];   // skT hi (sz8)
    __shared__ unsigned short sm_kl[64 * 64];   // skT lo (sz8)
    __shared__ unsigned short sm_vt[64 * 64];   // vT exact bf16 (sz8)
    const int idx = blockIdx.x;
    const int seg = idx & 15;
    const int bh  = idx >> 4;
    const int h   = bh & 15;
    const int b   = bh >> 4;
    const size_t base = ((size_t)b * T_ + (size_t)seg * SEG_ + (size_t)h * 32) * D_;
    const unsigned short* kt = kproj + base;
    const unsigned short* vt = vproj + base;
    const int t    = threadIdx.x;
    const int lane = t & 63;
    const int w    = t >> 6;
    const int c16  = lane & 15;
    const int g4   = lane >> 4;
    const int lr   = t >> 2;
    const int lc   = (t & 3) * 16;

    short8 bones;
#pragma unroll
    for (int j = 0; j < 8; ++j) bones[j] = (short)0x3F80;   // bf16 1.0

    f32x4 acc[4];                                // n-tiles 0..3 for m-tile w
#pragma unroll
    for (int nt = 0; nt < 4; ++nt) acc[nt] = (f32x4)0.f;
    f32x4 zacc = (f32x4)0.f;

    for (int c0 = 0; c0 < SEG_; c0 += 64) {
        __syncthreads();   // previous chunk's frag reads / vtg readback done
        {   // transpose-stage: lane = t-row, wave = 16-wide d-chunk.
            const int row = c0 + lane;
            const unsigned short* kp = kt + (size_t)row * 64 + w * 16;
            const unsigned short* vp = vt + (size_t)row * 64 + w * 16;
            ushort8 k0 = *(const ushort8*)kp, k1 = *(const ushort8*)(kp + 8);
            ushort8 v0 = *(const ushort8*)vp, v1 = *(const ushort8*)(vp + 8);
            const int tb = lane >> 3, tl = lane & 7;
#pragma unroll
            for (int e = 0; e < 8; ++e) {
                const float f0 = elu1(bf2f(k0[e]));
                const unsigned short h0 = f2bf(f0), l0 = f2bf(f0 - bf2f(h0));
                const float f1 = elu1(bf2f(k1[e]));
                const unsigned short h1 = f2bf(f1), l1 = f2bf(f1 - bf2f(h1));
                const int a0 = sz8(w * 16 + e,     tb) + tl;
                const int a1 = sz8(w * 16 + 8 + e, tb) + tl;
                sm_kh[a0] = h0; sm_kl[a0] = l0; sm_vt[a0] = v0[e];
                sm_kh[a1] = h1; sm_kl[a1] = l1; sm_vt[a1] = v1[e];
            }
        }
        __syncthreads();
        // MFMA: C[d][v] += skT[d][t] * vT[v][t], k-dim = t (2 k-steps of 32)
#pragma unroll
        for (int ks = 0; ks < 2; ++ks) {
            const short8 ahh = *(const short8*)&sm_kh[sz8(w * 16 + c16, ks * 4 + g4)];
            const short8 alo = *(const short8*)&sm_kl[sz8(w * 16 + c16, ks * 4 + g4)];
            zacc = __builtin_amdgcn_mfma_f32_16x16x32_bf16(ahh, bones, zacc, 0, 0, 0);
            zacc = __builtin_amdgcn_mfma_f32_16x16x32_bf16(alo, bones, zacc, 0, 0, 0);
#pragma unroll
            for (int nt = 0; nt < 4; ++nt) {
                const short8 bv = *(const short8*)&sm_vt[sz8(nt * 16 + c16, ks * 4 + g4)];
                acc[nt] = __builtin_amdgcn_mfma_f32_16x16x32_bf16(ahh, bv, acc[nt], 0, 0, 0);
                acc[nt] = __builtin_amdgcn_mfma_f32_16x16x32_bf16(alo, bv, acc[nt], 0, 0, 0);
            }
        }
        {   // vtg writeback for this chunk
            unsigned short* vo = vtg + ((size_t)idx * 64 + lr) * 512 + c0 + lc;
            *(ushort8*)vo       = *(const ushort8*)&sm_vt[sz8(lr, lc >> 3)];
            *(ushort8*)(vo + 8) = *(const ushort8*)&sm_vt[sz8(lr, (lc >> 3) + 1)];
        }
    }
    float* Mout = Mseg + (size_t)idx * 4096;
#pragma unroll
    for (int nt = 0; nt < 4; ++nt)
#pragma unroll
        for (int r = 0; r < 4; ++r)
            Mout[(size_t)(w * 16 + g4 * 4 + r) * 64 + nt * 16 + c16] = acc[nt][r];
    if (c16 == 0) {
#pragma unroll
        for (int r = 0; r < 4; ++r)
            zsum[(size_t)idx * 64 + w * 16 + g4 * 4 + r] = zacc[r];
    }
}

// Per (b,h,slice): in-place exclusive prefix of M (1024-float slice),
// inclusive prefix of z (slice 0). 128 blocks.
__global__ __launch_bounds__(256) void prefix_scan(
    float* __restrict__ M, float* __restrict__ z)
{
    const int blk = blockIdx.x;
    const int bh  = blk >> 2, sl = blk & 3;
    const int t   = threadIdx.x;
    const size_t off = (size_t)bh * NSEG_ * 4096 + (size_t)sl * 1024 + (size_t)t * 4;
    float4 run = make_float4(0.f, 0.f, 0.f, 0.f);
    float runz = 0.f;
    for (int seg = 0; seg < NSEG_; ++seg) {
        const size_t o = off + (size_t)seg * 4096;
        float4 m = *(const float4*)(M + o);
        *(float4*)(M + o) = run;
        run.x += m.x; run.y += m.y; run.z += m.z; run.w += m.w;
        if (sl == 0 && t < 64) {
            const size_t oz = ((size_t)bh * NSEG_ + seg) * 64 + t;
            runz += z[oz];
            z[oz] = runz;
        }
    }
}

// MFMA flash attention: ONE block per (b,h,seg). K/V^T/mem^T staged in LDS
// once; 4 q-sub-tiles of 128 rows (8 waves x 16); kb loop barrier-free.
__global__ __launch_bounds__(512) void attn_mfma(
    const unsigned short* __restrict__ qproj, const unsigned short* __restrict__ kproj,
    const unsigned short* __restrict__ vtg, const float* __restrict__ memb,
    const float* __restrict__ Zaf, const float* __restrict__ betas,
    unsigned short* __restrict__ ath, unsigned short* __restrict__ atl)
{
    __shared__ unsigned short smK[8 * 4096];   // K: 8 kb-tiles [64][64] sz8 (64KB)
    __shared__ unsigned short smV[8 * 4096];   // V^T: 8 kb-tiles [64][64] sz8 (64KB)
    __shared__ unsigned short smM[4096];       // mem^T [64][64] sz8 (8KB)
    __shared__ unsigned short smP[128 * 64];   // P publish + epilogue scratch (16KB)
    __shared__ float Zsh[64], gsh[64];

    const int rest = blockIdx.x;
    const int bh   = rest >> 4;
    const int seg  = rest & 15;
    const int h    = bh & 15;
    const int b    = bh >> 4;
    const size_t base = ((size_t)b * T_ + (size_t)seg * SEG_ + (size_t)h * 32) * D_;

    const int t    = threadIdx.x;
    const int lane = t & 63;
    const int w    = t >> 6;          // 0..7
    const int c16  = lane & 15;
    const int g4   = lane >> 4;
    const int sr   = t >> 3;          // staging row 0..63
    const int sg   = t & 7;           // staging granule 0..7

    const unsigned short* qt = qproj + base;
    const unsigned short* kt = kproj + base;
    const unsigned short* vt = vtg + (size_t)rest * (64 * 512);
    const float* mb = memb + (size_t)rest * 4096;

    if (t < 64) {
        Zsh[t] = Zaf[(size_t)rest * 64 + t];
        gsh[t] = 1.f / (1.f + __expf(-betas[h * 64 + t]));
    }

    // stage mem^T (bf16, transposed, sz8)
    {
        const float* mp = mb + (size_t)sr * 64 + sg * 8;
#pragma unroll
        for (int u = 0; u < 2; ++u) {
            float4 m4 = *(const float4*)(mp + u * 4);
            smM[sz8(sg * 8 + u * 4 + 0, sr >> 3) + (sr & 7)] = f2bf(m4.x);
            smM[sz8(sg * 8 + u * 4 + 1, sr >> 3) + (sr & 7)] = f2bf(m4.y);
            smM[sz8(sg * 8 + u * 4 + 2, sr >> 3) + (sr & 7)] = f2bf(m4.z);
            smM[sz8(sg * 8 + u * 4 + 3, sr >> 3) + (sr & 7)] = f2bf(m4.w);
        }
    }
    // stage K and V^T (raw 16B copies, sz8)
#pragma unroll
    for (int kb = 0; kb < 8; ++kb) {
        *(ushort8*)&smK[kb * 4096 + sz8(sr, sg)] =
            *(const ushort8*)(kt + (size_t)(kb * 64 + sr) * 64 + sg * 8);
        *(ushort8*)&smV[kb * 4096 + sz8(sr, sg)] =
            *(const ushort8*)(vt + (size_t)sr * 512 + kb * 64 + sg * 8);
    }
    __syncthreads();

    short8 bones;
#pragma unroll
    for (int j = 0; j < 8; ++j) bones[j] = (short)0x3F80;

#pragma unroll 1
    for (int qc2 = 0; qc2 < 4; ++qc2) {
        short8 qh[2], sqh[2];
        float rowsum = 0.f;
#pragma unroll
        for (int ks = 0; ks < 2; ++ks) {
            const unsigned short* qp =
                qt + (size_t)(qc2 * 128 + w * 16 + c16) * 64 + g4 * 8 + ks * 32;
            ushort8 qv = *(const ushort8*)qp;
            short8 qf, sf;
#pragma unroll
            for (int j = 0; j < 8; ++j) {
                float e = elu1(bf2f(qv[j]));
                rowsum += e;
                qf[j] = (short)qv[j];
                sf[j] = (short)f2bf(e);
            }
            qh[ks] = qf; sqh[ks] = sf;
        }
        rowsum += __shfl_xor(rowsum, 16);
        rowsum += __shfl_xor(rowsum, 32);

        f32x4 numf[4];
#pragma unroll
        for (int nf = 0; nf < 4; ++nf) numf[nf] = (f32x4)0.f;
#pragma unroll
        for (int ks = 0; ks < 2; ++ks)
#pragma unroll
            for (int nf = 0; nf < 4; ++nf) {
                short8 bm = *(const short8*)&smM[sz8(nf * 16 + c16, g4 + ks * 4)];
                numf[nf] = __builtin_amdgcn_mfma_f32_16x16x32_bf16(sqh[ks], bm, numf[nf], 0, 0, 0);
            }

        f32x4 o[4];
#pragma unroll
        for (int nf = 0; nf < 4; ++nf) o[nf] = (f32x4)0.f;
        float mrow[4] = {-1e30f, -1e30f, -1e30f, -1e30f};
        float lrow[4] = {0.f, 0.f, 0.f, 0.f};

#pragma unroll 1
        for (int kb = 0; kb < 8; ++kb) {
            f32x4 s[4];
#pragma unroll
            for (int nf = 0; nf < 4; ++nf) s[nf] = (f32x4)0.f;
#pragma unroll
            for (int ks = 0; ks < 2; ++ks)
#pragma unroll
                for (int nf = 0; nf < 4; ++nf) {
                    short8 bk = *(const short8*)&smK[kb * 4096 + sz8(nf * 16 + c16, g4 + ks * 4)];
                    s[nf] = __builtin_amdgcn_mfma_f32_16x16x32_bf16(qh[ks], bk, s[nf], 0, 0, 0);
                }
#pragma unroll
            for (int nf = 0; nf < 4; ++nf) s[nf] *= 0.125f;

            float pmax[4];
#pragma unroll
            for (int r = 0; r < 4; ++r)
                pmax[r] = fmaxf(fmaxf(s[0][r], s[1][r]), fmaxf(s[2][r], s[3][r]));
            const bool ok = pmax[0] <= mrow[0] + 8.f && pmax[1] <= mrow[1] + 8.f &&
                            pmax[2] <= mrow[2] + 8.f && pmax[3] <= mrow[3] + 8.f;
            if (!__all(ok)) {
#pragma unroll
                for (int r = 0; r < 4; ++r) {
                    float mx = pmax[r];
                    mx = fmaxf(mx, __shfl_xor(mx, 1));
                    mx = fmaxf(mx, __shfl_xor(mx, 2));
                    mx = fmaxf(mx, __shfl_xor(mx, 4));
                    mx = fmaxf(mx, __shfl_xor(mx, 8));
                    const float mnew = fmaxf(mrow[r], mx);
                    const float corr = __expf(mrow[r] - mnew);
                    mrow[r] = mnew;
                    lrow[r] *= corr;
#pragma unroll
                    for (int nf = 0; nf < 4; ++nf) o[nf][r] *= corr;
                }
            }
#pragma unroll
            for (int nf = 0; nf < 4; ++nf)
#pragma unroll
                for (int r = 0; r < 4; ++r) {
                    s[nf][r] = __expf(s[nf][r] - mrow[r]);
                    smP[sz8(w * 16 + g4 * 4 + r, nf * 2 + (c16 >> 3)) + (c16 & 7)] =
                        f2bf(s[nf][r]);
                }

            f32x4 psum = (f32x4)0.f;
#pragma unroll
            for (int ks = 0; ks < 2; ++ks) {
                short8 pa = *(const short8*)&smP[sz8(w * 16 + c16, g4 + ks * 4)];
                psum = __builtin_amdgcn_mfma_f32_16x16x32_bf16(pa, bones, psum, 0, 0, 0);
#pragma unroll
                for (int nf = 0; nf < 4; ++nf) {
                    short8 bv = *(const short8*)&smV[kb * 4096 + sz8(nf * 16 + c16, g4 + ks * 4)];
                    o[nf] = __builtin_amdgcn_mfma_f32_16x16x32_bf16(pa, bv, o[nf], 0, 0, 0);
                }
            }
#pragma unroll
            for (int r = 0; r < 4; ++r) lrow[r] += psum[r];
        }

        float rs[4], invl[4];
#pragma unroll
        for (int r = 0; r < 4; ++r) {
            rs[r]   = __shfl(rowsum, (g4 << 2) + r);
            invl[r] = 1.f / lrow[r];
        }
        float res[4][4];
#pragma unroll
        for (int nf = 0; nf < 4; ++nf) {
            const int col = nf * 16 + c16;
            const float Zc = Zsh[col], gc = gsh[col];
            const float izc = 1.f / Zc;
#pragma unroll
            for (int r = 0; r < 4; ++r) {
                const float adot = o[nf][r] * invl[r];
                const float amem = numf[nf][r] * izc / rs[r];
                res[nf][r] = gc * amem + (1.f - gc) * adot;
            }
        }
        const int orow = t >> 2, olc = (t & 3) * 16;
        const size_t ob = base + (size_t)(qc2 * 128 + orow) * 64 + olc;
#pragma unroll
        for (int nf = 0; nf < 4; ++nf)
#pragma unroll
            for (int r = 0; r < 4; ++r)
                smP[sz8(w * 16 + g4 * 4 + r, nf * 2 + (c16 >> 3)) + (c16 & 7)] =
                    f2bf(res[nf][r]);
        __syncthreads();
        *(ushort8*)(ath + ob)     = *(const ushort8*)&smP[sz8(orow, olc >> 3)];
        *(ushort8*)(ath + ob + 8) = *(const ushort8*)&smP[sz8(orow, (olc >> 3) + 1)];
        __syncthreads();
#pragma unroll
        for (int nf = 0; nf < 4; ++nf)
#pragma unroll
            for (int r = 0; r < 4; ++r) {
                const unsigned short hv = f2bf(res[nf][r]);
                smP[sz8(w * 16 + g4 * 4 + r, nf * 2 + (c16 >> 3)) + (c16 & 7)] =
                    f2bf(res[nf][r] - bf2f(hv));
            }
        __syncthreads();
        *(ushort8*)(atl + ob)     = *(const ushort8*)&smP[sz8(orow, olc >> 3)];
        *(ushort8*)(atl + ob + 8) = *(const ushort8*)&smP[sz8(orow, (olc >> 3) + 1)];
        __syncthreads();
    }
}

extern "C" void kernel_launch(void* const* d_in, const int* in_sizes, int n_in,
                              void* d_out, int out_size, void* d_ws, size_t ws_size,
                              hipStream_t stream) {
    const float* x     = (const float*)d_in[0];
    const float* Wq    = (const float*)d_in[1];
    const float* Wk    = (const float*)d_in[2];
    const float* Wv    = (const float*)d_in[3];
    const float* Wout  = (const float*)d_in[4];
    const float* betas = (const float*)d_in[5];
    float* out = (float*)d_out;
    (void)d_ws; (void)ws_size;

    float *M, *z;
    unsigned short *qb, *kb, *vb, *xh, *wqkv, *vt, *ath, *atl, *woh, *wol;
    hipGetSymbolAddress((void**)&qb,   HIP_SYMBOL(g_qb));
    hipGetSymbolAddress((void**)&kb,   HIP_SYMBOL(g_kb));
    hipGetSymbolAddress((void**)&vb,   HIP_SYMBOL(g_vb));
    hipGetSymbolAddress((void**)&xh,   HIP_SYMBOL(g_xh));
    hipGetSymbolAddress((void**)&wqkv, HIP_SYMBOL(g_wqkv));
    hipGetSymbolAddress((void**)&vt,   HIP_SYMBOL(g_vt));
    hipGetSymbolAddress((void**)&ath,  HIP_SYMBOL(g_ath));
    hipGetSymbolAddress((void**)&atl,  HIP_SYMBOL(g_atl));
    hipGetSymbolAddress((void**)&woh,  HIP_SYMBOL(g_woh));
    hipGetSymbolAddress((void**)&wol,  HIP_SYMBOL(g_wol));
    hipGetSymbolAddress((void**)&M,    HIP_SYMBOL(g_M));
    hipGetSymbolAddress((void**)&z,    HIP_SYMBOL(g_z));

    // fused prologue: x + Wq/Wk/Wv casts + Wout split in one launch
    const int nXB = (int)(NPROJ / 1024), nWB = (int)(NW / 1024);
    prep_cast<<<nXB + 4 * nWB, 256, 0, stream>>>(x, Wq, Wk, Wv, Wout,
                                                 xh, wqkv, woh, wol);

    gemm_qkv8<<<dim3(768), 512, 0, stream>>>(xh, wqkv, qb, kb, vb);
    seg_stats<<<B_ * H_ * NSEG_, 256, 0, stream>>>(kb, vb, M, z, vt);
    prefix_scan<<<B_ * H_ * 4, 256, 0, stream>>>(M, z);
    attn_mfma<<<B_ * H_ * NSEG_, 512, 0, stream>>>(qb, kb, vt, M, z, betas, ath, atl);
    gemm_bt8<<<dim3(256), 512, 0, stream>>>(ath, atl, woh, wol, out);
}